// Round 3
// baseline (11907.259 us; speedup 1.0000x reference)
//
#include <hip/hip_runtime.h>

typedef __attribute__((ext_vector_type(4))) float f4;
typedef __attribute__((ext_vector_type(8))) short frag8;
typedef unsigned long long u64;
typedef unsigned int u32;
typedef unsigned short u16;

#define ALPHA 0.3f

// ---- ws layout (bytes) ----
#define WHH_OFF   0ull                 // 3072*1024 bf16 = 6291456
#define WIH_OFF   6291456ull           // 3072*128 bf16  = 786432
#define HBUF_OFF  7077888ull           // 2 parities * 8 groups * 128KB = 2097152
#define ST1_OFF   9175040ull           // 256*2 fp32
#define ZERO_LEN  2097152ull           // hbuf only (tags must start at 0)

__device__ __forceinline__ u16 f2bf(float f) {
  u32 u = __float_as_uint(f);
  u32 r = (u + 0x7FFFu + ((u >> 16) & 1u)) >> 16;
  return (u16)r;
}
__device__ __forceinline__ float bf2f(u16 h) {
  return __uint_as_float(((u32)h) << 16);
}
__device__ __forceinline__ float sigmf(float x) {
  float e = __expf(-fabsf(x));
  float s = 1.0f / (1.0f + e);
  return x >= 0.f ? s : 1.0f - s;
}
__device__ __forceinline__ float tanhf_(float x) {
  float e = __expf(-2.0f * fabsf(x));
  float t = (1.0f - e) / (1.0f + e);
  return x >= 0.f ? t : -t;
}
__device__ __forceinline__ frag8 pack_bf16(f4 a, f4 b) {
  union { u16 h[8]; frag8 f; } u;
  u.h[0] = f2bf(a[0]); u.h[1] = f2bf(a[1]); u.h[2] = f2bf(a[2]); u.h[3] = f2bf(a[3]);
  u.h[4] = f2bf(b[0]); u.h[5] = f2bf(b[1]); u.h[6] = f2bf(b[2]); u.h[7] = f2bf(b[3]);
  return u.f;
}

// fp32 -> bf16 weight conversion (W_hh then W_ih), exact-sized grid.
__global__ void prep_bf16(const float* __restrict__ whh_f32,
                          const float* __restrict__ wih_f32,
                          u16* __restrict__ whh, u16* __restrict__ wih) {
  int i = blockIdx.x * 256 + threadIdx.x;
  const int nhh = 3072 * 1024;
  if (i < nhh) whh[i] = f2bf(whh_f32[i]);
  else         wih[i - nhh] = f2bf(wih_f32[i - nhh]);
}

// Persistent GRU. 256 WGs = 8 groups (batch slices of 32) x 32 WGs (32 H-cols).
// NO inter-WG barrier: h is exchanged as self-validating tagged u32
// (bf16 data << 16 | 16-bit step tag) via relaxed agent-scope atomics.
// Tags in a slot can only be t or t-2 (distance-2 dependency chain protects
// the 2-deep ping-pong), so tag==t validates a value. Readers poll their own
// data lines (fully distributed — no hot cachelines). One __syncthreads per
// step (LDS reduce buffer is double-buffered).
__global__ __launch_bounds__(256, 1) void gru_kernel(
    const float* __restrict__ x,       // [256][1024][128]
    const float* __restrict__ b_ih,    // [3072]
    const float* __restrict__ b_hh,    // [3072]
    const u16* __restrict__ whh,       // [3072][1024] bf16
    const u16* __restrict__ wih,       // [3072][128] bf16
    u64* __restrict__ hbuf,            // [2][8][16384] u64 (tagged pairs)
    float* __restrict__ st1)           // [256][2]
{
  __shared__ f4 xbuf[8192];            // 2 x 64 KB ping-pong reduce buffer
  const int wg = blockIdx.x;
  const int g = wg >> 5, w = wg & 31;
  const int tid = threadIdx.x;
  const int v = tid >> 6;              // wave = K-slice of 256
  const int l = tid & 63;
  const int lm = l & 15, lq = l >> 4;

  // ---- persistent weight fragments ----
  // B-frag 16x16x32: n = lane&15 -> gate row, k = (lane>>4)*8 + j
  frag8 whhf[8][6];
  frag8 wihf[6];
#pragma unroll
  for (int rt = 0; rt < 6; ++rt) {
    int grow = (rt >> 1) * 1024 + w * 32 + (rt & 1) * 16 + lm;
    wihf[rt] = *(const frag8*)(wih + grow * 128 + v * 32 + lq * 8);
#pragma unroll
    for (int kb = 0; kb < 8; ++kb)
      whhf[kb][rt] = *(const frag8*)(whh + grow * 1024 + v * 256 + kb * 32 + lq * 8);
  }

  // ---- update-phase constants: thread <-> (4 batches ub0.., col uc) ----
  const int uc = tid & 31;
  const int ub0 = (tid >> 5) << 2;
  const int colg = w * 32 + uc;
  const float bir = b_ih[colg],         bhr = b_hh[colg];
  const float biz = b_ih[1024 + colg],  bhz = b_hh[1024 + colg];
  const float bin_ = b_ih[2048 + colg], bhn = b_hh[2048 + colg];
  const int cb = colg >> 5, lqw = (colg >> 3) & 3, jw = colg & 7;
  f4 hprev = {0.f, 0.f, 0.f, 0.f};

  // ---- EMA state in A-frag order; x prefetched one step ahead ----
  f4 e0a, e0b, e1a, e1b;
  const float* xb0 = x + (size_t)(g * 32 + lm) * 131072 + v * 32 + lq * 8;
  const float* xb1 = x + (size_t)(g * 32 + 16 + lm) * 131072 + v * 32 + lq * 8;
  f4 xn0 = *(const f4*)xb0, xn1 = *(const f4*)(xb0 + 4);
  f4 xn2 = *(const f4*)xb1, xn3 = *(const f4*)(xb1 + 4);

  const float A1 = 1.0f - ALPHA;
  const f4 zz = {0.f, 0.f, 0.f, 0.f};
  f4 acc[2][6], accn[2][2];

#pragma unroll 1
  for (int t = 0; t < 1024; ++t) {
    const u64* hread = hbuf + (size_t)((t & 1) * 8 + g) * 16384;
    u32* hw32 = (u32*)(hbuf + (size_t)(((t + 1) & 1) * 8 + g) * 16384);
    const u32 tg = (u32)t;
    const u64 rep = (u64)tg | ((u64)tg << 32);

    // ---- issue first 4 kb-slots of tagged h loads (depth-4 pipeline) ----
    u64 q[4][8];
#pragma unroll
    for (int s = 0; s < 4; ++s) {
      int base0 = (((v * 8 + s) * 2 + 0) * 16 + lm) * 16 + lq * 4;
#pragma unroll
      for (int j = 0; j < 4; ++j) {
        q[s][j]     = __hip_atomic_load(hread + base0 + j,       __ATOMIC_RELAXED, __HIP_MEMORY_SCOPE_AGENT);
        q[s][4 + j] = __hip_atomic_load(hread + base0 + 256 + j, __ATOMIC_RELAXED, __HIP_MEMORY_SCOPE_AGENT);
      }
    }

    // ---- EMA (x_t prefetched last iter) + pack; all under slot-load latency ----
    if (t == 0) { e0a = xn0; e0b = xn1; e1a = xn2; e1b = xn3; }
    else {
      e0a = A1 * xn0 + ALPHA * e0a; e0b = A1 * xn1 + ALPHA * e0b;
      e1a = A1 * xn2 + ALPHA * e1a; e1b = A1 * xn3 + ALPHA * e1b;
    }
    frag8 smf0 = pack_bf16(e0a, e0b);
    frag8 smf1 = pack_bf16(e1a, e1b);

    // ---- prefetch x_{t+1} ----
    {
      size_t to = (size_t)(t < 1023 ? t + 1 : 1023) * 128;
      xn0 = *(const f4*)(xb0 + to); xn1 = *(const f4*)(xb0 + to + 4);
      xn2 = *(const f4*)(xb1 + to); xn3 = *(const f4*)(xb1 + to + 4);
    }

    // ---- init acc + gi MFMAs (still under load latency) ----
#pragma unroll
    for (int bh = 0; bh < 2; ++bh) {
#pragma unroll
      for (int rt = 0; rt < 6; ++rt) acc[bh][rt] = zz;
      accn[bh][0] = zz; accn[bh][1] = zz;
    }
#pragma unroll
    for (int rt = 0; rt < 4; ++rt) {
      acc[0][rt] = __builtin_amdgcn_mfma_f32_16x16x32_bf16(smf0, wihf[rt], acc[0][rt], 0, 0, 0);
      acc[1][rt] = __builtin_amdgcn_mfma_f32_16x16x32_bf16(smf1, wihf[rt], acc[1][rt], 0, 0, 0);
    }
#pragma unroll
    for (int nt = 0; nt < 2; ++nt) {
      accn[0][nt] = __builtin_amdgcn_mfma_f32_16x16x32_bf16(smf0, wihf[4 + nt], accn[0][nt], 0, 0, 0);
      accn[1][nt] = __builtin_amdgcn_mfma_f32_16x16x32_bf16(smf1, wihf[4 + nt], accn[1][nt], 0, 0, 0);
    }

    // ---- pipelined kb loop: validate slot, refill, 12 gh MFMAs ----
#pragma unroll
    for (int kb = 0; kb < 8; ++kb) {
      const int s = kb & 3;
      for (;;) {
        u64 bad = (q[s][0] ^ rep) | (q[s][1] ^ rep) | (q[s][2] ^ rep) | (q[s][3] ^ rep)
                | (q[s][4] ^ rep) | (q[s][5] ^ rep) | (q[s][6] ^ rep) | (q[s][7] ^ rep);
        bad &= 0x0000FFFF0000FFFFull;
        if (__ballot(bad != 0ull) == 0ull) break;
        int base0 = (((v * 8 + kb) * 2 + 0) * 16 + lm) * 16 + lq * 4;
#pragma unroll
        for (int j = 0; j < 4; ++j) {
          q[s][j]     = __hip_atomic_load(hread + base0 + j,       __ATOMIC_RELAXED, __HIP_MEMORY_SCOPE_AGENT);
          q[s][4 + j] = __hip_atomic_load(hread + base0 + 256 + j, __ATOMIC_RELAXED, __HIP_MEMORY_SCOPE_AGENT);
        }
      }
      frag8 af0, af1;
      {
        union { u32 d[4]; frag8 f; } ua, ub;
#pragma unroll
        for (int j = 0; j < 4; ++j) {
          ua.d[j] = __builtin_amdgcn_perm((u32)(q[s][j] >> 32),     (u32)q[s][j],     0x07060302u);
          ub.d[j] = __builtin_amdgcn_perm((u32)(q[s][4 + j] >> 32), (u32)q[s][4 + j], 0x07060302u);
        }
        af0 = ua.f; af1 = ub.f;
      }
      if (kb < 4) {   // refill ring slot with kb+4
        int kn = kb + 4;
        int base0 = (((v * 8 + kn) * 2 + 0) * 16 + lm) * 16 + lq * 4;
#pragma unroll
        for (int j = 0; j < 4; ++j) {
          q[s][j]     = __hip_atomic_load(hread + base0 + j,       __ATOMIC_RELAXED, __HIP_MEMORY_SCOPE_AGENT);
          q[s][4 + j] = __hip_atomic_load(hread + base0 + 256 + j, __ATOMIC_RELAXED, __HIP_MEMORY_SCOPE_AGENT);
        }
      }
#pragma unroll
      for (int rt = 0; rt < 6; ++rt) {
        acc[0][rt] = __builtin_amdgcn_mfma_f32_16x16x32_bf16(af0, whhf[kb][rt], acc[0][rt], 0, 0, 0);
        acc[1][rt] = __builtin_amdgcn_mfma_f32_16x16x32_bf16(af1, whhf[kb][rt], acc[1][rt], 0, 0, 0);
      }
    }

    // ---- write K-partials to LDS ping-pong (XOR-swizzled b128) ----
    f4* xb = xbuf + (t & 1) * 4096;
#pragma unroll
    for (int bh = 0; bh < 2; ++bh) {
      int b8 = bh * 4 + lq;
#pragma unroll
      for (int rt = 0; rt < 6; ++rt) {
        int gr = rt * 16 + lm;
        xb[((v * 128 + gr) << 3) | (b8 ^ (gr & 7))] = acc[bh][rt];
      }
#pragma unroll
      for (int nt = 0; nt < 2; ++nt) {
        int gr = 96 + nt * 16 + lm;
        xb[((v * 128 + gr) << 3) | (b8 ^ (gr & 7))] = accn[bh][nt];
      }
    }
    __syncthreads();   // the ONLY barrier per step

    // ---- gate update: 4 batches x 1 col per thread ----
    int swz = (ub0 >> 2) ^ (uc & 7);
    f4 sr = zz, sz4 = zz, gn4 = zz, gin4 = zz;
#pragma unroll
    for (int vv = 0; vv < 4; ++vv) {
      sr   += xb[((vv * 128 + uc) << 3) | swz];
      sz4  += xb[((vv * 128 + 32 + uc) << 3) | swz];
      gn4  += xb[((vv * 128 + 64 + uc) << 3) | swz];
      gin4 += xb[((vv * 128 + 96 + uc) << 3) | swz];
    }
    f4 h4;
#pragma unroll
    for (int i = 0; i < 4; ++i) {
      float rr = sigmf(sr[i] + bir + bhr);
      float zg = sigmf(sz4[i] + biz + bhz);
      float nn = tanhf_(gin4[i] + bin_ + rr * (gn4[i] + bhn));
      h4[i] = (1.0f - zg) * nn + zg * hprev[i];
    }
    hprev = h4;

    // ---- fire-and-forget tagged h store (no drain, no signal) ----
    u32 tgw = (u32)(t + 1) & 0xFFFFu;
#pragma unroll
    for (int i = 0; i < 4; ++i) {
      int b = ub0 + i;
      u32 val = ((u32)f2bf(h4[i]) << 16) | tgw;
      int idx = ((cb * 2 + (b >> 4)) * 16 + (b & 15)) * 32 + lqw * 8 + jw;
      __hip_atomic_store(hw32 + idx, val, __ATOMIC_RELAXED, __HIP_MEMORY_SCOPE_AGENT);
    }
  }

  // st_1 columns 1,2 (fp32) for denorm; EMA regs hold state at t=1023
  if (w == 0 && v == 0 && lq == 0) {
    st1[(g * 32 + lm) * 2 + 0] = e0a[1];
    st1[(g * 32 + lm) * 2 + 1] = e0a[2];
    st1[(g * 32 + 16 + lm) * 2 + 0] = e1a[1];
    st1[(g * 32 + 16 + lm) * 2 + 1] = e1a[2];
  }
}

// out[b][o] = (h_T[b] . W_fc[o] + b_fc[o] - a*st1[b][o]) / (1-a)
__global__ void fc_kernel(const u32* __restrict__ hbuf32,  // parity-0 tagged
                          const float* __restrict__ wfc,   // [2][1024]
                          const float* __restrict__ bfc,   // [2]
                          const float* __restrict__ st1,   // [256][2]
                          float* __restrict__ out)         // [256][2]
{
  int b = blockIdx.x, t = threadIdx.x;
  int g = b >> 5, bl = b & 31;
  int k0 = t * 4;
  int idx = (((k0 >> 5) * 2 + (bl >> 4)) * 16 + (bl & 15)) * 32 + ((k0 >> 3) & 3) * 8 + (k0 & 7);
  const u32* hp = hbuf32 + (size_t)g * 32768 + idx;
  float h0 = bf2f((u16)(hp[0] >> 16)), h1 = bf2f((u16)(hp[1] >> 16));
  float h2 = bf2f((u16)(hp[2] >> 16)), h3 = bf2f((u16)(hp[3] >> 16));
  float s0 = h0 * wfc[k0] + h1 * wfc[k0 + 1] + h2 * wfc[k0 + 2] + h3 * wfc[k0 + 3];
  float s1 = h0 * wfc[1024 + k0] + h1 * wfc[1024 + k0 + 1] +
             h2 * wfc[1024 + k0 + 2] + h3 * wfc[1024 + k0 + 3];
#pragma unroll
  for (int off = 32; off > 0; off >>= 1) {
    s0 += __shfl_down(s0, off);
    s1 += __shfl_down(s1, off);
  }
  __shared__ float red[8];
  if ((t & 63) == 0) { red[(t >> 6) * 2] = s0; red[(t >> 6) * 2 + 1] = s1; }
  __syncthreads();
  if (t == 0) {
    float a0 = red[0] + red[2] + red[4] + red[6] + bfc[0];
    float a1 = red[1] + red[3] + red[5] + red[7] + bfc[1];
    float inv = 1.0f / (1.0f - ALPHA);
    out[b * 2 + 0] = (a0 - ALPHA * st1[b * 2 + 0]) * inv;
    out[b * 2 + 1] = (a1 - ALPHA * st1[b * 2 + 1]) * inv;
  }
}

extern "C" void kernel_launch(void* const* d_in, const int* in_sizes, int n_in,
                              void* d_out, int out_size, void* d_ws, size_t ws_size,
                              hipStream_t stream) {
  const float* x   = (const float*)d_in[0];
  const float* Wih = (const float*)d_in[1];
  const float* Whh = (const float*)d_in[2];
  const float* bih = (const float*)d_in[3];
  const float* bhh = (const float*)d_in[4];
  const float* Wfc = (const float*)d_in[5];
  const float* bfc = (const float*)d_in[6];
  char* ws = (char*)d_ws;
  u16* whh_bf = (u16*)(ws + WHH_OFF);
  u16* wih_bf = (u16*)(ws + WIH_OFF);
  u64* hbuf   = (u64*)(ws + HBUF_OFF);
  float* st1  = (float*)(ws + ST1_OFF);

  hipMemsetAsync(ws + HBUF_OFF, 0, ZERO_LEN, stream);   // tags start at 0 = step-0 valid
  prep_bf16<<<13824, 256, 0, stream>>>(Whh, Wih, whh_bf, wih_bf);
  gru_kernel<<<256, 256, 0, stream>>>(x, bih, bhh, whh_bf, wih_bf, hbuf, st1);
  fc_kernel<<<256, 256, 0, stream>>>((const u32*)(ws + HBUF_OFF), Wfc, bfc, st1,
                                     (float*)d_out);
}